// Round 1
// baseline (347.477 us; speedup 1.0000x reference)
//
#include <hip/hip_runtime.h>

// ---------------- constants ----------------
#define BATCH   131072
#define INDIM   1024
#define HDIM    384
#define LDIM    128
#define KSLOT   32
#define BDIM    512
#define BM      128
#define NBLK    (BATCH / BM)          // 1024

// LDS layout (bytes)
#define Z_OFF     0                   // z1 [128][392] bf16 (100352 B); later fused [128][264]
#define STG_OFF   100352
#define XT_OFF    (STG_OFF)           // ph1 xt [128][40] bf16 (10240)
#define WT_OFF    (STG_OFF + 10240)   // ph1 wt [384][40] bf16 (30720)
#define W2T_OFF   (STG_OFF)           // ph2 w2t [128][40] (10240)
#define LG_OFF    (STG_OFF + 10240)   // logits [128][32] f32 (16384)
#define W3T_OFF   (STG_OFF)           // ph3 w3t [384][40] (30720)
#define CB_OFF    141312
#define SMEM_BYTES 157184

typedef unsigned short u16;
typedef u16    u16x8  __attribute__((ext_vector_type(8)));
typedef __bf16 bf16x8 __attribute__((ext_vector_type(8)));
typedef float  f32x4  __attribute__((ext_vector_type(4)));

__device__ __forceinline__ u16 f2bf(float f) {
  unsigned u = __float_as_uint(f);
  u += 0x7FFFu + ((u >> 16) & 1u);    // round-to-nearest-even
  return (u16)(u >> 16);
}

__device__ __forceinline__ float gelu_exact(float v) {
  return 0.5f * v * (1.0f + erff(v * 0.70710678118654752440f));
}

__device__ __forceinline__ f32x4 mfma16(u16x8 a, u16x8 b, f32x4 c) {
  return __builtin_amdgcn_mfma_f32_16x16x32_bf16(
      __builtin_bit_cast(bf16x8, a), __builtin_bit_cast(bf16x8, b), c, 0, 0, 0);
}

// ---------------- prep: transpose + bf16-cast weights ----------------
// w1T [384][1024], w2T [128][384], w3T [384][256]
__global__ void prep_kernel(const float* __restrict__ w1, const float* __restrict__ w2,
                            const float* __restrict__ w3, u16* __restrict__ w1T,
                            u16* __restrict__ w2T, u16* __restrict__ w3T) {
  int i = blockIdx.x * 256 + threadIdx.x;
  if (i < 393216) {                       // 384*1024
    int n = i >> 10, k = i & 1023;
    w1T[i] = f2bf(w1[k * 384 + n]);
  } else if (i < 442368) {                // + 128*384
    int j = i - 393216;
    int n = j / 384, k = j - n * 384;
    w2T[j] = f2bf(w2[k * 128 + n]);
  } else if (i < 540672) {                // + 384*256
    int j = i - 442368;
    int n = j >> 8, k = j & 255;
    w3T[j] = f2bf(w3[k * 384 + n]);
  }
}

// ---------------- fused forward ----------------
__global__ __launch_bounds__(BDIM, 2) void fused_kernel(
    const float* __restrict__ x,  const u16* __restrict__ w1T,
    const float* __restrict__ b1, const u16* __restrict__ w2T,
    const float* __restrict__ b2, const float* __restrict__ mkw,
    const float* __restrict__ mvw, const u16* __restrict__ w3T,
    const float* __restrict__ b3, const float* __restrict__ w4,
    const float* __restrict__ b4, float* __restrict__ out) {
  extern __shared__ char smem[];
  u16*   zbuf = (u16*)(smem + Z_OFF);     // stride 392 (z1), later stride 264 (fused)
  u16*   xt   = (u16*)(smem + XT_OFF);    // [128][40]
  u16*   wt   = (u16*)(smem + WT_OFF);    // [384][40]
  u16*   w2t  = (u16*)(smem + W2T_OFF);   // [128][40]
  float* lgs  = (float*)(smem + LG_OFF);  // [128][32]
  u16*   w3t  = (u16*)(smem + W3T_OFF);   // [384][40]
  float* b1s  = (float*)(smem + CB_OFF);
  float* b2s  = (float*)(smem + CB_OFF + 1536);
  float* b3s  = (float*)(smem + CB_OFF + 2048);
  float* w4s  = (float*)(smem + CB_OFF + 3584);
  u16*   mks  = (u16*)(smem + CB_OFF + 5120);       // [32][136]
  float* rowpart = (float*)(smem + CB_OFF + 13824); // [128][4]

  const int tid  = threadIdx.x;
  const int lane = tid & 63;
  const int wid  = tid >> 6;
  const int l15  = lane & 15;
  const int g    = lane >> 4;
  const int waveM = wid >> 2;   // 0..1
  const int waveN = wid & 3;    // 0..3
  const int row0 = blockIdx.x * BM;

  // ---- stage small constants into LDS ----
  for (int i = tid; i < 384; i += BDIM) b1s[i] = b1[i];
  for (int i = tid; i < 128; i += BDIM) b2s[i] = b2[i];
  for (int i = tid; i < 384; i += BDIM) b3s[i] = b3[i];
  for (int i = tid; i < 384; i += BDIM) w4s[i] = w4[i];
  {
    int r = tid >> 4, c = (tid & 15) * 8;  // 32 rows x 128 cols / 8
    const float4* p = (const float4*)(mkw + r * 128 + c);
    float4 a = p[0], b = p[1];
    u16x8 v;
    v[0]=f2bf(a.x); v[1]=f2bf(a.y); v[2]=f2bf(a.z); v[3]=f2bf(a.w);
    v[4]=f2bf(b.x); v[5]=f2bf(b.y); v[6]=f2bf(b.z); v[7]=f2bf(b.w);
    *(u16x8*)(mks + r * 136 + c) = v;
  }

  // =========== GEMM1: z1 = gelu(x @ w1 + b1)  [128 x 384], K=1024 ===========
  const int sr = tid >> 2;            // 0..127
  const int sc = (tid & 3) * 8;       // 0,8,16,24
  const long xbase = (long)(row0 + sr) * INDIM + sc;
  float4 xA, xB; u16x8 wA, wB, wC;
  {
    const float* p = x + xbase;
    xA = *(const float4*)p; xB = *(const float4*)(p + 4);
    const u16* q = w1T + sr * 1024 + sc;
    wA = *(const u16x8*)q;
    wB = *(const u16x8*)(q + 131072);
    wC = *(const u16x8*)(q + 262144);
  }
  f32x4 acc[4][6];
  #pragma unroll
  for (int m = 0; m < 4; ++m)
    #pragma unroll
    for (int n = 0; n < 6; ++n) acc[m][n] = (f32x4){0.f, 0.f, 0.f, 0.f};

  const int aoff = (waveM * 64 + l15) * 40 + g * 8;
  const int boff = (waveN * 96 + l15) * 40 + g * 8;

  for (int kt = 0; kt < 32; ++kt) {
    {   // write staged regs (loaded last iter) to LDS
      u16x8 v;
      v[0]=f2bf(xA.x); v[1]=f2bf(xA.y); v[2]=f2bf(xA.z); v[3]=f2bf(xA.w);
      v[4]=f2bf(xB.x); v[5]=f2bf(xB.y); v[6]=f2bf(xB.z); v[7]=f2bf(xB.w);
      *(u16x8*)(xt + sr * 40 + sc) = v;
      *(u16x8*)(wt + sr * 40 + sc) = wA;
      *(u16x8*)(wt + (sr + 128) * 40 + sc) = wB;
      *(u16x8*)(wt + (sr + 256) * 40 + sc) = wC;
    }
    if (kt < 31) {  // prefetch next K-tile
      const float* p = x + xbase + (kt + 1) * 32;
      xA = *(const float4*)p; xB = *(const float4*)(p + 4);
      const u16* q = w1T + sr * 1024 + sc + (kt + 1) * 32;
      wA = *(const u16x8*)q;
      wB = *(const u16x8*)(q + 131072);
      wC = *(const u16x8*)(q + 262144);
    }
    __syncthreads();
    u16x8 af[4], bfr[6];
    #pragma unroll
    for (int m = 0; m < 4; ++m) af[m] = *(const u16x8*)(xt + aoff + m * (16 * 40));
    #pragma unroll
    for (int n = 0; n < 6; ++n) bfr[n] = *(const u16x8*)(wt + boff + n * (16 * 40));
    #pragma unroll
    for (int m = 0; m < 4; ++m)
      #pragma unroll
      for (int n = 0; n < 6; ++n)
        acc[m][n] = mfma16(af[m], bfr[n], acc[m][n]);
    __syncthreads();
  }
  // epilogue: z1 (bf16) into zbuf stride 392
  #pragma unroll
  for (int m = 0; m < 4; ++m) {
    #pragma unroll
    for (int n = 0; n < 6; ++n) {
      int col = waveN * 96 + n * 16 + l15;
      float bias = b1s[col];
      #pragma unroll
      for (int j = 0; j < 4; ++j) {
        int row = waveM * 64 + m * 16 + g * 4 + j;
        zbuf[row * 392 + col] = f2bf(gelu_exact(acc[m][n][j] + bias));
      }
    }
  }
  __syncthreads();

  // =========== GEMM2: z = gelu(z1 @ w2 + b2)  [128 x 128], K=384 ===========
  f32x4 acc2[4][2];
  #pragma unroll
  for (int m = 0; m < 4; ++m) { acc2[m][0] = (f32x4){0,0,0,0}; acc2[m][1] = (f32x4){0,0,0,0}; }
  const int a2off = (waveM * 64 + l15) * 392 + g * 8;
  const int b2off = (waveN * 32 + l15) * 40 + g * 8;
  for (int kt = 0; kt < 12; ++kt) {
    int k0 = kt * 32;
    *(u16x8*)(w2t + sr * 40 + sc) = *(const u16x8*)(w2T + sr * 384 + k0 + sc);
    __syncthreads();
    u16x8 a2f[4], b2f[2];
    #pragma unroll
    for (int m = 0; m < 4; ++m) a2f[m] = *(const u16x8*)(zbuf + a2off + m * (16 * 392) + k0);
    #pragma unroll
    for (int n = 0; n < 2; ++n) b2f[n] = *(const u16x8*)(w2t + b2off + n * (16 * 40));
    #pragma unroll
    for (int m = 0; m < 4; ++m)
      #pragma unroll
      for (int n = 0; n < 2; ++n)
        acc2[m][n] = mfma16(a2f[m], b2f[n], acc2[m][n]);
    __syncthreads();
  }
  // epilogue: write z into fused buffer (stride 264), cols 0..127 — aliases z1 (all reads done)
  u16* fz = zbuf;
  #pragma unroll
  for (int m = 0; m < 4; ++m) {
    #pragma unroll
    for (int n = 0; n < 2; ++n) {
      int col = waveN * 32 + n * 16 + l15;
      float bias = b2s[col];
      #pragma unroll
      for (int j = 0; j < 4; ++j) {
        int row = waveM * 64 + m * 16 + g * 4 + j;
        fz[row * 264 + col] = f2bf(gelu_exact(acc2[m][n][j] + bias));
      }
    }
  }
  __syncthreads();

  // =========== logits = (z @ mk^T)/tau  [128 x 32] ===========
  {
    f32x4 accl[2] = {(f32x4){0,0,0,0}, (f32x4){0,0,0,0}};
    const int alo = (wid * 16 + l15) * 264 + g * 8;
    const int blo = l15 * 136 + g * 8;
    #pragma unroll
    for (int ks = 0; ks < 4; ++ks) {
      u16x8 a  = *(const u16x8*)(fz + alo + ks * 32);
      u16x8 q0 = *(const u16x8*)(mks + blo + ks * 32);
      u16x8 q1 = *(const u16x8*)(mks + blo + 16 * 136 + ks * 32);
      accl[0] = mfma16(a, q0, accl[0]);
      accl[1] = mfma16(a, q1, accl[1]);
    }
    #pragma unroll
    for (int n = 0; n < 2; ++n)
      #pragma unroll
      for (int j = 0; j < 4; ++j)
        lgs[(wid * 16 + g * 4 + j) * 32 + n * 16 + l15] = accl[n][j] * (1.0f / 0.7f);
  }
  __syncthreads();

  // =========== top-2 + 2-way softmax + mem = a1*mv[i1] + a2*mv[i2] ===========
  {
    int row = tid >> 2, q = tid & 3;
    const float* lp = lgs + row * 32 + q * 8;
    float m1 = -3.4e38f, m2 = -3.4e38f; int i1 = -1, i2 = -1;
    #pragma unroll
    for (int s = 0; s < 8; ++s) {
      float v = lp[s]; int idx = q * 8 + s;
      if (v > m1) { m2 = m1; i2 = i1; m1 = v; i1 = idx; }
      else if (v > m2) { m2 = v; i2 = idx; }
    }
    #pragma unroll
    for (int d = 1; d <= 2; d <<= 1) {
      float om1 = __shfl_xor(m1, d); int oi1 = __shfl_xor(i1, d);
      float om2 = __shfl_xor(m2, d); int oi2 = __shfl_xor(i2, d);
      bool take = (om1 > m1) || (om1 == m1 && oi1 < i1);
      if (take) {
        float nm2; int ni2;
        if (m1 > om2 || (m1 == om2 && i1 < oi2)) { nm2 = m1; ni2 = i1; }
        else { nm2 = om2; ni2 = oi2; }
        m1 = om1; i1 = oi1; m2 = nm2; i2 = ni2;
      } else {
        if (om1 > m2 || (om1 == m2 && oi1 < i2)) { m2 = om1; i2 = oi1; }
      }
    }
    float a1 = 1.0f / (1.0f + expf(m2 - m1));
    float a2 = 1.0f - a1;
    const float4* v1 = (const float4*)(mvw + i1 * 128 + q * 32);
    const float4* v2 = (const float4*)(mvw + i2 * 128 + q * 32);
    #pragma unroll
    for (int c = 0; c < 4; ++c) {
      float4 pa = v1[c * 2], pb = v1[c * 2 + 1];
      float4 ra = v2[c * 2], rb = v2[c * 2 + 1];
      u16x8 o;
      o[0] = f2bf(a1 * pa.x + a2 * ra.x); o[1] = f2bf(a1 * pa.y + a2 * ra.y);
      o[2] = f2bf(a1 * pa.z + a2 * ra.z); o[3] = f2bf(a1 * pa.w + a2 * ra.w);
      o[4] = f2bf(a1 * pb.x + a2 * rb.x); o[5] = f2bf(a1 * pb.y + a2 * rb.y);
      o[6] = f2bf(a1 * pb.z + a2 * rb.z); o[7] = f2bf(a1 * pb.w + a2 * rb.w);
      *(u16x8*)(fz + row * 264 + 128 + q * 32 + c * 8) = o;
    }
  }
  __syncthreads();

  // =========== GEMM3: h = gelu(fused @ w3 + b3)  [128 x 384], K=256 ===========
  f32x4 acc3[4][6];
  #pragma unroll
  for (int m = 0; m < 4; ++m)
    #pragma unroll
    for (int n = 0; n < 6; ++n) acc3[m][n] = (f32x4){0.f, 0.f, 0.f, 0.f};
  const int a3off = (waveM * 64 + l15) * 264 + g * 8;
  const int b3off = (waveN * 96 + l15) * 40 + g * 8;
  for (int kt = 0; kt < 8; ++kt) {
    int k0 = kt * 32;
    *(u16x8*)(w3t + sr * 40 + sc)         = *(const u16x8*)(w3T + sr * 256 + k0 + sc);
    *(u16x8*)(w3t + (sr + 128) * 40 + sc) = *(const u16x8*)(w3T + (sr + 128) * 256 + k0 + sc);
    *(u16x8*)(w3t + (sr + 256) * 40 + sc) = *(const u16x8*)(w3T + (sr + 256) * 256 + k0 + sc);
    __syncthreads();
    u16x8 a3f[4], b3f[6];
    #pragma unroll
    for (int m = 0; m < 4; ++m) a3f[m] = *(const u16x8*)(fz + a3off + m * (16 * 264) + k0);
    #pragma unroll
    for (int n = 0; n < 6; ++n) b3f[n] = *(const u16x8*)(w3t + b3off + n * (16 * 40));
    #pragma unroll
    for (int m = 0; m < 4; ++m)
      #pragma unroll
      for (int n = 0; n < 6; ++n)
        acc3[m][n] = mfma16(a3f[m], b3f[n], acc3[m][n]);
    __syncthreads();
  }
  // epilogue: per-row dot with w4 via 16-lane shuffle reduce
  #pragma unroll
  for (int m = 0; m < 4; ++m) {
    float s0 = 0.f, s1 = 0.f, s2 = 0.f, s3 = 0.f;
    #pragma unroll
    for (int n = 0; n < 6; ++n) {
      int col = waveN * 96 + n * 16 + l15;
      float bias = b3s[col], wv = w4s[col];
      s0 += gelu_exact(acc3[m][n][0] + bias) * wv;
      s1 += gelu_exact(acc3[m][n][1] + bias) * wv;
      s2 += gelu_exact(acc3[m][n][2] + bias) * wv;
      s3 += gelu_exact(acc3[m][n][3] + bias) * wv;
    }
    #pragma unroll
    for (int d = 1; d < 16; d <<= 1) {
      s0 += __shfl_xor(s0, d); s1 += __shfl_xor(s1, d);
      s2 += __shfl_xor(s2, d); s3 += __shfl_xor(s3, d);
    }
    if (l15 == 0) {
      int rb = waveM * 64 + m * 16 + g * 4;
      rowpart[(rb + 0) * 4 + waveN] = s0;
      rowpart[(rb + 1) * 4 + waveN] = s1;
      rowpart[(rb + 2) * 4 + waveN] = s2;
      rowpart[(rb + 3) * 4 + waveN] = s3;
    }
  }
  __syncthreads();
  if (tid < BM) {
    float lg = rowpart[tid * 4] + rowpart[tid * 4 + 1] + rowpart[tid * 4 + 2] +
               rowpart[tid * 4 + 3] + b4[0];
    out[row0 + tid] = 1.0f / (1.0f + expf(-lg));
  }
}

// ---------------- launch ----------------
extern "C" void kernel_launch(void* const* d_in, const int* in_sizes, int n_in,
                              void* d_out, int out_size, void* d_ws, size_t ws_size,
                              hipStream_t stream) {
  const float* x  = (const float*)d_in[0];
  const float* w1 = (const float*)d_in[1];
  const float* b1 = (const float*)d_in[2];
  const float* w2 = (const float*)d_in[3];
  const float* b2 = (const float*)d_in[4];
  const float* mk = (const float*)d_in[5];
  const float* mv = (const float*)d_in[6];
  const float* w3 = (const float*)d_in[7];
  const float* b3 = (const float*)d_in[8];
  const float* w4 = (const float*)d_in[9];
  const float* b4 = (const float*)d_in[10];

  u16* w1T = (u16*)d_ws;            // 393216 elems
  u16* w2T = w1T + 393216;          // 49152 elems
  u16* w3T = w1T + 442368;          // 98304 elems

  prep_kernel<<<2112, 256, 0, stream>>>(w1, w2, w3, w1T, w2T, w3T);

  (void)hipFuncSetAttribute(reinterpret_cast<const void*>(fused_kernel),
                            hipFuncAttributeMaxDynamicSharedMemorySize, SMEM_BYTES);
  fused_kernel<<<NBLK, BDIM, SMEM_BYTES, stream>>>(x, w1T, b1, w2T, b2, mk, mv, w3T,
                                                   b3, w4, b4, (float*)d_out);
}

// Round 2
// 331.963 us; speedup vs baseline: 1.0467x; 1.0467x over previous
//
#include <hip/hip_runtime.h>

// ---------------- constants ----------------
#define BATCH   131072
#define INDIM   1024
#define BM      64
#define BDIM    256
#define NBLK    (BATCH / BM)          // 2048

// ---- LDS layout (bytes), region [0,58368) is phase-multiplexed ----
#define WT_OFF   0                    // GEMM1 w-tile [384][64] bf16 (49152)
#define XT_OFF   49152                // GEMM1 x-tile [64][64]  bf16 (8192)
#define Z1_OFF   0                    // z1 [64][392] bf16 (50176)
#define W2T_OFF  50176                // GEMM2 w-tile [128][32] (8192)
#define FZ_OFF   0                    // fused [64][264] bf16 (33792)
#define LG_OFF   33792                // logits [64][33] f32 (8448)
#define W3T_OFF  33792                // GEMM3 w-tile [384][32] (24576)
#define CB_OFF   58368
#define B1S_OFF  (CB_OFF)             // 384 f32
#define B2S_OFF  (CB_OFF + 1536)      // 128 f32
#define B3S_OFF  (CB_OFF + 2048)      // 384 f32
#define W4S_OFF  (CB_OFF + 3584)      // 384 f32
#define MKS_OFF  (CB_OFF + 5120)      // mk bf16 [32][136] (8704)
#define RP_OFF   (CB_OFF + 13824)     // rowpart [64][4] f32 (1024)
#define SMEM_BYTES (CB_OFF + 14848)   // 73216 -> 2 blocks/CU

typedef unsigned short u16;
typedef u16    u16x8  __attribute__((ext_vector_type(8)));
typedef __bf16 bf16x8 __attribute__((ext_vector_type(8)));
typedef float  f32x4  __attribute__((ext_vector_type(4)));

__device__ __forceinline__ u16 f2bf(float f) {
  unsigned u = __float_as_uint(f);
  u += 0x7FFFu + ((u >> 16) & 1u);    // RNE
  return (u16)(u >> 16);
}

__device__ __forceinline__ float gelu_exact(float v) {
  return 0.5f * v * (1.0f + erff(v * 0.70710678118654752440f));
}

__device__ __forceinline__ f32x4 mfma16(u16x8 a, u16x8 b, f32x4 c) {
  return __builtin_amdgcn_mfma_f32_16x16x32_bf16(
      __builtin_bit_cast(bf16x8, a), __builtin_bit_cast(bf16x8, b), c, 0, 0, 0);
}

__device__ __forceinline__ u16x8 cvt8(float4 a, float4 b) {
  bf16x8 r;
  r[0]=(__bf16)a.x; r[1]=(__bf16)a.y; r[2]=(__bf16)a.z; r[3]=(__bf16)a.w;
  r[4]=(__bf16)b.x; r[5]=(__bf16)b.y; r[6]=(__bf16)b.z; r[7]=(__bf16)b.w;
  return __builtin_bit_cast(u16x8, r);
}

typedef __attribute__((address_space(3))) unsigned int       lds_u32;
typedef __attribute__((address_space(1))) const unsigned int glb_u32;
__device__ __forceinline__ void gload16(const void* g, void* l) {
  // per-wave: lane i's 16B from g land at (uniform l) + i*16
  __builtin_amdgcn_global_load_lds((glb_u32*)g, (lds_u32*)l, 16, 0, 0);
}

// ---------------- prep: bf16-cast + transpose + tile + swizzle ----------------
// w1s: 16 tiles of [384 rows(n)][8 chunks], chunk c' holds source k-chunk c'^(r&7)
// w2s: 12 tiles of [128][4 chunks], c'^( (r>>1)&3 )
// w3s:  8 tiles of [384][4 chunks], c'^( (r>>1)&3 )
__global__ void prep_kernel(const float* __restrict__ w1, const float* __restrict__ w2,
                            const float* __restrict__ w3, u16* __restrict__ w1s,
                            u16* __restrict__ w2s, u16* __restrict__ w3s) {
  int i = blockIdx.x * 256 + threadIdx.x;
  if (i < 393216) {
    int kt = i / 24576, p = i % 24576;
    int r = p >> 6, q = p & 63, cp = q >> 3, o = q & 7;
    int k = kt * 64 + ((cp ^ (r & 7)) << 3) + o;
    w1s[i] = f2bf(w1[k * 384 + r]);
  } else if (i < 442368) {
    int j = i - 393216;
    int kt = j / 4096, p = j % 4096;
    int r = p >> 5, q = p & 31, cp = q >> 3, o = q & 7;
    int k = kt * 32 + ((cp ^ ((r >> 1) & 3)) << 3) + o;
    w2s[j] = f2bf(w2[k * 128 + r]);
  } else if (i < 540672) {
    int j = i - 442368;
    int kt = j / 12288, p = j % 12288;
    int r = p >> 5, q = p & 31, cp = q >> 3, o = q & 7;
    int k = kt * 32 + ((cp ^ ((r >> 1) & 3)) << 3) + o;
    w3s[j] = f2bf(w3[k * 384 + r]);
  }
}

// ---------------- fused forward ----------------
__global__ __launch_bounds__(BDIM, 2) void fused_kernel(
    const float* __restrict__ x,  const u16* __restrict__ w1s,
    const float* __restrict__ b1, const u16* __restrict__ w2s,
    const float* __restrict__ b2, const float* __restrict__ mkw,
    const float* __restrict__ mvw, const u16* __restrict__ w3s,
    const float* __restrict__ b3, const float* __restrict__ w4,
    const float* __restrict__ b4, float* __restrict__ out) {
  extern __shared__ char smem[];
  u16*   wt  = (u16*)(smem + WT_OFF);
  u16*   xt  = (u16*)(smem + XT_OFF);
  u16*   z1  = (u16*)(smem + Z1_OFF);
  u16*   w2t = (u16*)(smem + W2T_OFF);
  u16*   fz  = (u16*)(smem + FZ_OFF);
  float* lgs = (float*)(smem + LG_OFF);
  u16*   w3t = (u16*)(smem + W3T_OFF);
  float* b1s = (float*)(smem + B1S_OFF);
  float* b2s = (float*)(smem + B2S_OFF);
  float* b3s = (float*)(smem + B3S_OFF);
  float* w4s = (float*)(smem + W4S_OFF);
  u16*   mks = (u16*)(smem + MKS_OFF);
  float* rowpart = (float*)(smem + RP_OFF);

  const int tid  = threadIdx.x;
  const int lane = tid & 63;
  const int wid  = tid >> 6;          // 0..3 == waveN
  const int l15  = lane & 15;
  const int g    = lane >> 4;         // 0..3
  const int aswz = l15 & 7;
  const int bsw2 = (l15 >> 1) & 3;
  const int row0 = blockIdx.x * BM;

  // ---- stage constants ----
  for (int i = tid; i < 384; i += BDIM) b1s[i] = b1[i];
  for (int i = tid; i < 128; i += BDIM) b2s[i] = b2[i];
  for (int i = tid; i < 384; i += BDIM) b3s[i] = b3[i];
  for (int i = tid; i < 384; i += BDIM) w4s[i] = w4[i];
  {
    int r = tid >> 3, cc = (tid & 7) * 16;   // 32 rows x 128 / 16
    const float4* p = (const float4*)(mkw + r * 128 + cc);
    float4 a = p[0], b = p[1], c = p[2], d = p[3];
    *(u16x8*)(mks + r * 136 + cc)     = cvt8(a, b);
    *(u16x8*)(mks + r * 136 + cc + 8) = cvt8(c, d);
  }

  // =========== GEMM1: z1 = gelu(x @ w1 + b1)  [64 x 384], K=1024, BK=64 ===========
  const int sr = tid >> 2;            // 0..63
  const int sj = tid & 3;
  const int ss = sr & 7;
  const int csw = (2 * sj) ^ ss;      // swizzled chunk for lo half
  const float* xq = x + (long)(row0 + sr) * INDIM + sj * 16;
  float4 xr0 = *(const float4*)xq, xr1 = *(const float4*)(xq + 4),
         xr2 = *(const float4*)(xq + 8), xr3 = *(const float4*)(xq + 12);

  f32x4 acc[4][6];
  #pragma unroll
  for (int m = 0; m < 4; ++m)
    #pragma unroll
    for (int n = 0; n < 6; ++n) acc[m][n] = (f32x4){0.f, 0.f, 0.f, 0.f};

  for (int kt = 0; kt < 16; ++kt) {
    __syncthreads();                          // staging buffers free
    {   // w-tile DMA: 49152 B, 12288 B per wave
      const u16* wsrc = w1s + kt * 24576 + wid * 6144 + lane * 8;
      u16* wdst = wt + wid * 6144;
      #pragma unroll
      for (int i = 0; i < 12; ++i) gload16(wsrc + i * 512, wdst + i * 512);
    }
    {   // x-tile: convert regs -> swizzled chunks
      u16x8 lo = cvt8(xr0, xr1), hi = cvt8(xr2, xr3);
      *(u16x8*)(xt + sr * 64 + csw * 8)       = lo;
      *(u16x8*)(xt + sr * 64 + (csw ^ 1) * 8) = hi;
    }
    __syncthreads();                          // drain DMA + x writes
    if (kt < 15) {                            // prefetch next x (lands under MFMA)
      const float* p = xq + (kt + 1) * 64;
      xr0 = *(const float4*)p;      xr1 = *(const float4*)(p + 4);
      xr2 = *(const float4*)(p + 8); xr3 = *(const float4*)(p + 12);
    }
    __builtin_amdgcn_s_setprio(1);
    #pragma unroll
    for (int ks = 0; ks < 2; ++ks) {
      u16x8 af[4], bfr[6];
      #pragma unroll
      for (int m = 0; m < 4; ++m)
        af[m] = *(const u16x8*)(xt + (m * 16 + l15) * 64 + (((g + 4 * ks) ^ aswz)) * 8);
      #pragma unroll
      for (int n = 0; n < 6; ++n)
        bfr[n] = *(const u16x8*)(wt + (wid * 96 + n * 16 + l15) * 64 + (((g + 4 * ks) ^ aswz)) * 8);
      #pragma unroll
      for (int m = 0; m < 4; ++m)
        #pragma unroll
        for (int n = 0; n < 6; ++n)
          acc[m][n] = mfma16(af[m], bfr[n], acc[m][n]);
    }
    __builtin_amdgcn_s_setprio(0);
  }
  __syncthreads();                            // staging reads done -> z1 may overwrite
  #pragma unroll
  for (int m = 0; m < 4; ++m) {
    #pragma unroll
    for (int n = 0; n < 6; ++n) {
      int col = wid * 96 + n * 16 + l15;
      float bias = b1s[col];
      #pragma unroll
      for (int j = 0; j < 4; ++j)
        z1[(m * 16 + g * 4 + j) * 392 + col] = f2bf(gelu_exact(acc[m][n][j] + bias));
    }
  }

  // =========== GEMM2: z = gelu(z1 @ w2 + b2)  [64 x 128], K=384, BK=32 ===========
  f32x4 acc2[4][2];
  #pragma unroll
  for (int m = 0; m < 4; ++m) { acc2[m][0] = (f32x4){0,0,0,0}; acc2[m][1] = (f32x4){0,0,0,0}; }
  for (int kt = 0; kt < 12; ++kt) {
    __syncthreads();                          // z1 visible / prev B reads done
    {   // w2 tile DMA: 8192 B, 2048 per wave
      const u16* s2 = w2s + kt * 4096 + wid * 1024 + lane * 8;
      u16* d2 = w2t + wid * 1024;
      gload16(s2, d2); gload16(s2 + 512, d2 + 512);
    }
    u16x8 a2f[4];
    #pragma unroll
    for (int m = 0; m < 4; ++m)
      a2f[m] = *(const u16x8*)(z1 + (m * 16 + l15) * 392 + kt * 32 + g * 8);
    __syncthreads();                          // drain DMA
    u16x8 b2f[2];
    #pragma unroll
    for (int n = 0; n < 2; ++n)
      b2f[n] = *(const u16x8*)(w2t + (wid * 32 + n * 16 + l15) * 32 + (g ^ bsw2) * 8);
    #pragma unroll
    for (int m = 0; m < 4; ++m)
      #pragma unroll
      for (int n = 0; n < 2; ++n)
        acc2[m][n] = mfma16(a2f[m], b2f[n], acc2[m][n]);
  }
  __syncthreads();                            // z1 reads done -> fz may overwrite
  #pragma unroll
  for (int m = 0; m < 4; ++m) {
    #pragma unroll
    for (int n = 0; n < 2; ++n) {
      int col = wid * 32 + n * 16 + l15;
      float bias = b2s[col];
      #pragma unroll
      for (int j = 0; j < 4; ++j)
        fz[(m * 16 + g * 4 + j) * 264 + col] = f2bf(gelu_exact(acc2[m][n][j] + bias));
    }
  }
  __syncthreads();

  // =========== logits = (z @ mk^T)/tau  [64 x 32] ===========
  {
    f32x4 accl[2] = {(f32x4){0,0,0,0}, (f32x4){0,0,0,0}};
    const int alo = (wid * 16 + l15) * 264 + g * 8;
    const int blo = l15 * 136 + g * 8;
    #pragma unroll
    for (int ks = 0; ks < 4; ++ks) {
      u16x8 a  = *(const u16x8*)(fz + alo + ks * 32);
      u16x8 q0 = *(const u16x8*)(mks + blo + ks * 32);
      u16x8 q1 = *(const u16x8*)(mks + blo + 16 * 136 + ks * 32);
      accl[0] = mfma16(a, q0, accl[0]);
      accl[1] = mfma16(a, q1, accl[1]);
    }
    #pragma unroll
    for (int n = 0; n < 2; ++n)
      #pragma unroll
      for (int j = 0; j < 4; ++j)
        lgs[(wid * 16 + g * 4 + j) * 33 + n * 16 + l15] = accl[n][j] * (1.0f / 0.7f);
  }
  __syncthreads();

  // =========== top-2 + 2-way softmax + mem ===========
  {
    int row = tid >> 2, q = tid & 3;
    const float* lp = lgs + row * 33 + q * 8;
    float m1 = -3.4e38f, m2 = -3.4e38f; int i1 = -1, i2 = -1;
    #pragma unroll
    for (int s = 0; s < 8; ++s) {
      float v = lp[s]; int idx = q * 8 + s;
      if (v > m1) { m2 = m1; i2 = i1; m1 = v; i1 = idx; }
      else if (v > m2) { m2 = v; i2 = idx; }
    }
    #pragma unroll
    for (int d = 1; d <= 2; d <<= 1) {
      float om1 = __shfl_xor(m1, d); int oi1 = __shfl_xor(i1, d);
      float om2 = __shfl_xor(m2, d); int oi2 = __shfl_xor(i2, d);
      bool take = (om1 > m1) || (om1 == m1 && oi1 < i1);
      if (take) {
        float nm2; int ni2;
        if (m1 > om2 || (m1 == om2 && i1 < oi2)) { nm2 = m1; ni2 = i1; }
        else { nm2 = om2; ni2 = oi2; }
        m1 = om1; i1 = oi1; m2 = nm2; i2 = ni2;
      } else {
        if (om1 > m2 || (om1 == m2 && oi1 < i2)) { m2 = om1; i2 = oi1; }
      }
    }
    float a1 = 1.0f / (1.0f + expf(m2 - m1));
    float a2 = 1.0f - a1;
    const float4* v1 = (const float4*)(mvw + i1 * 128 + q * 32);
    const float4* v2 = (const float4*)(mvw + i2 * 128 + q * 32);
    #pragma unroll
    for (int c = 0; c < 4; ++c) {
      float4 pa = v1[c * 2], pb = v1[c * 2 + 1];
      float4 ra = v2[c * 2], rb = v2[c * 2 + 1];
      u16x8 o;
      o[0] = f2bf(a1 * pa.x + a2 * ra.x); o[1] = f2bf(a1 * pa.y + a2 * ra.y);
      o[2] = f2bf(a1 * pa.z + a2 * ra.z); o[3] = f2bf(a1 * pa.w + a2 * ra.w);
      o[4] = f2bf(a1 * pb.x + a2 * rb.x); o[5] = f2bf(a1 * pb.y + a2 * rb.y);
      o[6] = f2bf(a1 * pb.z + a2 * rb.z); o[7] = f2bf(a1 * pb.w + a2 * rb.w);
      *(u16x8*)(fz + row * 264 + 128 + q * 32 + c * 8) = o;
    }
  }

  // =========== GEMM3: h = gelu(fused @ w3 + b3)  [64 x 384], K=256, BK=32 ===========
  f32x4 acc3[4][6];
  #pragma unroll
  for (int m = 0; m < 4; ++m)
    #pragma unroll
    for (int n = 0; n < 6; ++n) acc3[m][n] = (f32x4){0.f, 0.f, 0.f, 0.f};
  for (int kt = 0; kt < 8; ++kt) {
    __syncthreads();                          // mem writes visible / lgs dead / prev B reads done
    {   // w3 tile DMA: 24576 B, 6144 per wave
      const u16* s3 = w3s + kt * 12288 + wid * 3072 + lane * 8;
      u16* d3 = w3t + wid * 3072;
      #pragma unroll
      for (int i = 0; i < 6; ++i) gload16(s3 + i * 512, d3 + i * 512);
    }
    u16x8 a3f[4];
    #pragma unroll
    for (int m = 0; m < 4; ++m)
      a3f[m] = *(const u16x8*)(fz + (m * 16 + l15) * 264 + kt * 32 + g * 8);
    __syncthreads();                          // drain DMA
    u16x8 b3f[6];
    #pragma unroll
    for (int n = 0; n < 6; ++n)
      b3f[n] = *(const u16x8*)(w3t + (wid * 96 + n * 16 + l15) * 32 + (g ^ bsw2) * 8);
    #pragma unroll
    for (int m = 0; m < 4; ++m)
      #pragma unroll
      for (int n = 0; n < 6; ++n)
        acc3[m][n] = mfma16(a3f[m], b3f[n], acc3[m][n]);
  }

  // epilogue: per-row dot with w4, 16-lane shuffle reduce
  #pragma unroll
  for (int m = 0; m < 4; ++m) {
    float s0 = 0.f, s1 = 0.f, s2 = 0.f, s3 = 0.f;
    #pragma unroll
    for (int n = 0; n < 6; ++n) {
      int col = wid * 96 + n * 16 + l15;
      float bias = b3s[col], wv = w4s[col];
      s0 += gelu_exact(acc3[m][n][0] + bias) * wv;
      s1 += gelu_exact(acc3[m][n][1] + bias) * wv;
      s2 += gelu_exact(acc3[m][n][2] + bias) * wv;
      s3 += gelu_exact(acc3[m][n][3] + bias) * wv;
    }
    #pragma unroll
    for (int d = 1; d < 16; d <<= 1) {
      s0 += __shfl_xor(s0, d); s1 += __shfl_xor(s1, d);
      s2 += __shfl_xor(s2, d); s3 += __shfl_xor(s3, d);
    }
    if (l15 == 0) {
      int rb = m * 16 + g * 4;
      rowpart[(rb + 0) * 4 + wid] = s0;
      rowpart[(rb + 1) * 4 + wid] = s1;
      rowpart[(rb + 2) * 4 + wid] = s2;
      rowpart[(rb + 3) * 4 + wid] = s3;
    }
  }
  __syncthreads();
  if (tid < BM) {
    float lg = rowpart[tid * 4] + rowpart[tid * 4 + 1] + rowpart[tid * 4 + 2] +
               rowpart[tid * 4 + 3] + b4[0];
    out[row0 + tid] = 1.0f / (1.0f + expf(-lg));
  }
}

// ---------------- launch ----------------
extern "C" void kernel_launch(void* const* d_in, const int* in_sizes, int n_in,
                              void* d_out, int out_size, void* d_ws, size_t ws_size,
                              hipStream_t stream) {
  const float* x  = (const float*)d_in[0];
  const float* w1 = (const float*)d_in[1];
  const float* b1 = (const float*)d_in[2];
  const float* w2 = (const float*)d_in[3];
  const float* b2 = (const float*)d_in[4];
  const float* mk = (const float*)d_in[5];
  const float* mv = (const float*)d_in[6];
  const float* w3 = (const float*)d_in[7];
  const float* b3 = (const float*)d_in[8];
  const float* w4 = (const float*)d_in[9];
  const float* b4 = (const float*)d_in[10];

  u16* w1s = (u16*)d_ws;            // 393216 u16 (16 swizzled tiles)
  u16* w2s = w1s + 393216;          // 49152
  u16* w3s = w1s + 442368;          // 98304

  prep_kernel<<<2112, 256, 0, stream>>>(w1, w2, w3, w1s, w2s, w3s);

  (void)hipFuncSetAttribute(reinterpret_cast<const void*>(fused_kernel),
                            hipFuncAttributeMaxDynamicSharedMemorySize, SMEM_BYTES);
  fused_kernel<<<NBLK, BDIM, SMEM_BYTES, stream>>>(x, w1s, b1, w2s, b2, mk, mv, w3s,
                                                   b3, w4, b4, (float*)d_out);
}

// Round 3
// 283.808 us; speedup vs baseline: 1.2243x; 1.1697x over previous
//
#include <hip/hip_runtime.h>

// ---------------- constants ----------------
#define BATCH   131072
#define INDIM   1024
#define BM      64
#define BDIM    256
#define NBLK    (BATCH / BM)          // 2048

// ---- LDS layout (bytes), phase-multiplexed ----
#define WT_OFF   0                    // GEMM1 w-tile [384][64] bf16 (49152)
#define XT0_OFF  49152                // GEMM1 x-tile buf0 [64][64] (8192)
#define XT1_OFF  57344                // GEMM1 x-tile buf1 (8192) -> ends 65536
#define Z1_OFF   0                    // z1 [64][392] bf16 (50176)
#define W2T_OFF  50176                // GEMM2 w-tile [128][64] (16384) -> ends 66560
#define FZ_OFF   0                    // fused [64][264] bf16 (33792)
#define LG_OFF   33792                // logits [64][33] f32 (8448)
#define W3T_OFF  33792                // GEMM3 w-tile [384][32] (24576) -> ends 58368
#define RP_OFF   0                    // rowpart [64][4] f32 (aliases fz after barrier)
#define CB_OFF   66560
#define B1S_OFF  (CB_OFF)             // 384 f32
#define B2S_OFF  (CB_OFF + 1536)      // 128 f32
#define B3S_OFF  (CB_OFF + 2048)      // 384 f32
#define W4S_OFF  (CB_OFF + 3584)      // 384 f32
#define MKS_OFF  (CB_OFF + 5120)      // mk bf16 [32][136] (8704)
#define SMEM_BYTES (CB_OFF + 13824)   // 80384 -> 2 blocks/CU (2x80896 <= 163840)

typedef unsigned short u16;
typedef u16    u16x8  __attribute__((ext_vector_type(8)));
typedef __bf16 bf16x8 __attribute__((ext_vector_type(8)));
typedef float  f32x4  __attribute__((ext_vector_type(4)));

__device__ __forceinline__ u16 f2bf(float f) {
  unsigned u = __float_as_uint(f);
  u += 0x7FFFu + ((u >> 16) & 1u);    // RNE
  return (u16)(u >> 16);
}

__device__ __forceinline__ float gelu_exact(float v) {
  return 0.5f * v * (1.0f + erff(v * 0.70710678118654752440f));
}

__device__ __forceinline__ f32x4 mfma16(u16x8 a, u16x8 b, f32x4 c) {
  return __builtin_amdgcn_mfma_f32_16x16x32_bf16(
      __builtin_bit_cast(bf16x8, a), __builtin_bit_cast(bf16x8, b), c, 0, 0, 0);
}

__device__ __forceinline__ u16x8 cvt8(float4 a, float4 b) {
  bf16x8 r;
  r[0]=(__bf16)a.x; r[1]=(__bf16)a.y; r[2]=(__bf16)a.z; r[3]=(__bf16)a.w;
  r[4]=(__bf16)b.x; r[5]=(__bf16)b.y; r[6]=(__bf16)b.z; r[7]=(__bf16)b.w;
  return __builtin_bit_cast(u16x8, r);
}

typedef __attribute__((address_space(3))) unsigned int       lds_u32;
typedef __attribute__((address_space(1))) const unsigned int glb_u32;
__device__ __forceinline__ void gload16(const void* g, void* l) {
  __builtin_amdgcn_global_load_lds((glb_u32*)g, (lds_u32*)l, 16, 0, 0);
}

// barrier helpers: counted vmcnt BEFORE s_barrier (per-wave DMA publish), sched fence after
#define BARRIER_VMN(N) do { \
  asm volatile("s_waitcnt vmcnt(" #N ") lgkmcnt(0)" ::: "memory"); \
  __builtin_amdgcn_s_barrier(); \
  __builtin_amdgcn_sched_barrier(0); } while (0)
#define WAIT_VM0 do { \
  asm volatile("s_waitcnt vmcnt(0)" ::: "memory"); \
  __builtin_amdgcn_sched_barrier(0); } while (0)
#define WAIT_LGKM0 asm volatile("s_waitcnt lgkmcnt(0)" ::: "memory")
#define FENCE_SCHED __builtin_amdgcn_sched_barrier(0)

// ---------------- prep: bf16-cast + transpose + tile + swizzle ----------------
// w1s: 16 tiles [384 rows][8 chunks of 8], stored chunk c' holds k-chunk c'^(r&7)
// w2s:  6 tiles [128 rows][8 chunks of 8], c'^(r&7)
// w3s:  8 tiles [384 rows][4 chunks of 8], c'^((r>>1)&3)
__global__ void prep_kernel(const float* __restrict__ w1, const float* __restrict__ w2,
                            const float* __restrict__ w3, u16* __restrict__ w1s,
                            u16* __restrict__ w2s, u16* __restrict__ w3s) {
  int i = blockIdx.x * 256 + threadIdx.x;
  if (i < 393216) {
    int kt = i / 24576, p = i % 24576;
    int r = p >> 6, q = p & 63, cp = q >> 3, o = q & 7;
    int k = kt * 64 + ((cp ^ (r & 7)) << 3) + o;
    w1s[i] = f2bf(w1[k * 384 + r]);
  } else if (i < 442368) {
    int j = i - 393216;
    int kt = j / 8192, p = j % 8192;
    int r = p >> 6, q = p & 63, cp = q >> 3, o = q & 7;
    int k = kt * 64 + ((cp ^ (r & 7)) << 3) + o;
    w2s[j] = f2bf(w2[k * 128 + r]);
  } else if (i < 540672) {
    int j = i - 442368;
    int kt = j / 12288, p = j % 12288;
    int r = p >> 5, q = p & 31, cp = q >> 3, o = q & 7;
    int k = kt * 32 + ((cp ^ ((r >> 1) & 3)) << 3) + o;
    w3s[j] = f2bf(w3[k * 384 + r]);
  }
}

// ---------------- fused forward ----------------
__global__ __launch_bounds__(BDIM, 2) void fused_kernel(
    const float* __restrict__ x,  const u16* __restrict__ w1s,
    const float* __restrict__ b1, const u16* __restrict__ w2s,
    const float* __restrict__ b2, const float* __restrict__ mkw,
    const float* __restrict__ mvw, const u16* __restrict__ w3s,
    const float* __restrict__ b3, const float* __restrict__ w4,
    const float* __restrict__ b4, float* __restrict__ out) {
  extern __shared__ char smem[];
  u16*   wt  = (u16*)(smem + WT_OFF);
  u16*   z1  = (u16*)(smem + Z1_OFF);
  u16*   w2t = (u16*)(smem + W2T_OFF);
  u16*   fz  = (u16*)(smem + FZ_OFF);
  float* lgs = (float*)(smem + LG_OFF);
  u16*   w3t = (u16*)(smem + W3T_OFF);
  float* b1s = (float*)(smem + B1S_OFF);
  float* b2s = (float*)(smem + B2S_OFF);
  float* b3s = (float*)(smem + B3S_OFF);
  float* w4s = (float*)(smem + W4S_OFF);
  u16*   mks = (u16*)(smem + MKS_OFF);
  float* rowpart = (float*)(smem + RP_OFF);

  const int tid  = threadIdx.x;
  const int lane = tid & 63;
  const int wid  = tid >> 6;          // 0..3 == waveN
  const int l15  = lane & 15;
  const int g    = lane >> 4;         // 0..3
  const int aswz = l15 & 7;
  const int bsw2 = (l15 >> 1) & 3;
  const int row0 = blockIdx.x * BM;

  const int sr = tid >> 2;            // 0..63
  const int sj = tid & 3;
  const int csw = (2 * sj) ^ (sr & 7);

  // ---------- prologue: start tile-0 DMA + x(0) loads, stage constants under them ----------
  u16* wdst = wt + wid * 6144;
  {
    const u16* ws = w1s + wid * 6144 + lane * 8;
    #pragma unroll
    for (int i = 0; i < 12; ++i) gload16(ws + i * 512, wdst + i * 512);
  }
  FENCE_SCHED;
  const float* xq = x + (long)(row0 + sr) * INDIM + sj * 16;
  float4 xr0 = *(const float4*)xq,       xr1 = *(const float4*)(xq + 4),
         xr2 = *(const float4*)(xq + 8), xr3 = *(const float4*)(xq + 12);

  for (int i = tid; i < 384; i += BDIM) b1s[i] = b1[i];
  for (int i = tid; i < 128; i += BDIM) b2s[i] = b2[i];
  for (int i = tid; i < 384; i += BDIM) b3s[i] = b3[i];
  for (int i = tid; i < 384; i += BDIM) w4s[i] = w4[i];
  {
    int r = tid >> 3, cc = (tid & 7) * 16;
    const float4* p = (const float4*)(mkw + r * 128 + cc);
    float4 a = p[0], b = p[1], c = p[2], d = p[3];
    *(u16x8*)(mks + r * 136 + cc)     = cvt8(a, b);
    *(u16x8*)(mks + r * 136 + cc + 8) = cvt8(c, d);
  }
  {   // write xt[0] from x(0)
    u16* xn = (u16*)(smem + XT0_OFF);
    u16x8 lo = cvt8(xr0, xr1), hi = cvt8(xr2, xr3);
    *(u16x8*)(xn + sr * 64 + csw * 8)       = lo;
    *(u16x8*)(xn + sr * 64 + (csw ^ 1) * 8) = hi;
  }
  {   // load x(1) into regs
    const float* p = xq + 64;
    xr0 = *(const float4*)p;       xr1 = *(const float4*)(p + 4);
    xr2 = *(const float4*)(p + 8); xr3 = *(const float4*)(p + 12);
  }
  BARRIER_VMN(4);   // tile-0 DMA done (mine); xt[0] published; x(1) still in flight

  // =========== GEMM1: z1 = gelu(x @ w1 + b1)  [64 x 384], K=1024, BK=64 ===========
  f32x4 acc[4][6];
  #pragma unroll
  for (int m = 0; m < 4; ++m)
    #pragma unroll
    for (int n = 0; n < 6; ++n) acc[m][n] = (f32x4){0.f, 0.f, 0.f, 0.f};

  for (int kt = 0; kt < 16; ++kt) {
    // a) fragment reads (tile kt): xt[cur] cross-wave, wt own quarter
    const u16* xb = (u16*)(smem + ((kt & 1) ? XT1_OFF : XT0_OFF));
    u16x8 af[2][4], bfr[2][6];
    #pragma unroll
    for (int ks = 0; ks < 2; ++ks) {
      const int kc = ((g + 4 * ks) ^ aswz) * 8;
      #pragma unroll
      for (int m = 0; m < 4; ++m)
        af[ks][m] = *(const u16x8*)(xb + (m * 16 + l15) * 64 + kc);
      #pragma unroll
      for (int n = 0; n < 6; ++n)
        bfr[ks][n] = *(const u16x8*)(wt + (wid * 96 + n * 16 + l15) * 64 + kc);
    }
    WAIT_LGKM0;                     // frags landed -> my wt quarter & xt[cur] reads done
    if (kt < 15) {
      // b) next w-tile DMA into my own quarter (no barrier needed: self-read-only)
      const u16* ws = w1s + (kt + 1) * 24576 + wid * 6144 + lane * 8;
      #pragma unroll
      for (int i = 0; i < 12; ++i) gload16(ws + i * 512, wdst + i * 512);
      FENCE_SCHED;                  // pin DMA before x loads in vmcnt FIFO
      // c) publish xt[next] from xr (= x(kt+1))
      u16* xn = (u16*)(smem + ((kt & 1) ? XT0_OFF : XT1_OFF));
      u16x8 lo = cvt8(xr0, xr1), hi = cvt8(xr2, xr3);
      *(u16x8*)(xn + sr * 64 + csw * 8)       = lo;
      *(u16x8*)(xn + sr * 64 + (csw ^ 1) * 8) = hi;
      if (kt < 14) {                // d) stream x(kt+2)
        const float* p = xq + (kt + 2) * 64;
        xr0 = *(const float4*)p;       xr1 = *(const float4*)(p + 4);
        xr2 = *(const float4*)(p + 8); xr3 = *(const float4*)(p + 12);
      }
    }
    // e) MFMA burst (covers DMA flight time)
    __builtin_amdgcn_s_setprio(1);
    #pragma unroll
    for (int ks = 0; ks < 2; ++ks)
      #pragma unroll
      for (int m = 0; m < 4; ++m)
        #pragma unroll
        for (int n = 0; n < 6; ++n)
          acc[m][n] = mfma16(af[ks][m], bfr[ks][n], acc[m][n]);
    __builtin_amdgcn_s_setprio(0);
    // f) single barrier per iter; counted vmcnt keeps x-stream in flight
    if (kt < 14)       BARRIER_VMN(4);
    else if (kt == 14) BARRIER_VMN(0);
  }
  __syncthreads();                  // all waves past tile-15 reads -> staging region reusable

  // GEMM2 tile-0 DMA early (lands under z1 epilogue)
  {
    const u16* s2 = w2s + wid * 2048 + lane * 8;
    u16* d2 = w2t + wid * 2048;
    #pragma unroll
    for (int i = 0; i < 4; ++i) gload16(s2 + i * 512, d2 + i * 512);
  }
  // z1 epilogue
  #pragma unroll
  for (int m = 0; m < 4; ++m) {
    #pragma unroll
    for (int n = 0; n < 6; ++n) {
      int col = wid * 96 + n * 16 + l15;
      float bias = b1s[col];
      #pragma unroll
      for (int j = 0; j < 4; ++j)
        z1[(m * 16 + g * 4 + j) * 392 + col] = f2bf(gelu_exact(acc[m][n][j] + bias));
    }
  }
  BARRIER_VMN(0);                   // z1 published; my w2 tile-0 landed

  // =========== GEMM2: z = gelu(z1 @ w2 + b2)  [64 x 128], K=384, BK=64, NO barriers ===========
  f32x4 acc2[4][2];
  #pragma unroll
  for (int m = 0; m < 4; ++m) { acc2[m][0] = (f32x4){0,0,0,0}; acc2[m][1] = (f32x4){0,0,0,0}; }
  for (int kt = 0; kt < 6; ++kt) {
    u16x8 a2f[2][4], b2f[2][2];
    #pragma unroll
    for (int ks = 0; ks < 2; ++ks) {
      #pragma unroll
      for (int m = 0; m < 4; ++m)
        a2f[ks][m] = *(const u16x8*)(z1 + (m * 16 + l15) * 392 + kt * 64 + ks * 32 + g * 8);
      const int kc = ((g + 4 * ks) ^ aswz) * 8;
      #pragma unroll
      for (int n = 0; n < 2; ++n)
        b2f[ks][n] = *(const u16x8*)(w2t + (wid * 32 + n * 16 + l15) * 64 + kc);
    }
    WAIT_LGKM0;                     // my reads done -> my quarter overwrite safe
    if (kt < 5) {
      const u16* s2 = w2s + (kt + 1) * 8192 + wid * 2048 + lane * 8;
      u16* d2 = w2t + wid * 2048;
      #pragma unroll
      for (int i = 0; i < 4; ++i) gload16(s2 + i * 512, d2 + i * 512);
    }
    __builtin_amdgcn_s_setprio(1);
    #pragma unroll
    for (int ks = 0; ks < 2; ++ks)
      #pragma unroll
      for (int m = 0; m < 4; ++m)
        #pragma unroll
        for (int n = 0; n < 2; ++n)
          acc2[m][n] = mfma16(a2f[ks][m], b2f[ks][n], acc2[m][n]);
    __builtin_amdgcn_s_setprio(0);
    if (kt < 5) WAIT_VM0;           // my next tile landed (per-wave, no barrier)
  }
  __syncthreads();                  // all z1 reads done -> fz may overwrite
  #pragma unroll
  for (int m = 0; m < 4; ++m) {
    #pragma unroll
    for (int n = 0; n < 2; ++n) {
      int col = wid * 32 + n * 16 + l15;
      float bias = b2s[col];
      #pragma unroll
      for (int j = 0; j < 4; ++j)
        fz[(m * 16 + g * 4 + j) * 264 + col] = f2bf(gelu_exact(acc2[m][n][j] + bias));
    }
  }
  __syncthreads();                  // fz published

  // =========== logits = (z @ mk^T)/tau  [64 x 32]  (wave-local rows) ===========
  {
    f32x4 accl[2] = {(f32x4){0,0,0,0}, (f32x4){0,0,0,0}};
    const int alo = (wid * 16 + l15) * 264 + g * 8;
    const int blo = l15 * 136 + g * 8;
    #pragma unroll
    for (int ks = 0; ks < 4; ++ks) {
      u16x8 a  = *(const u16x8*)(fz + alo + ks * 32);
      u16x8 q0 = *(const u16x8*)(mks + blo + ks * 32);
      u16x8 q1 = *(const u16x8*)(mks + blo + 16 * 136 + ks * 32);
      accl[0] = mfma16(a, q0, accl[0]);
      accl[1] = mfma16(a, q1, accl[1]);
    }
    #pragma unroll
    for (int n = 0; n < 2; ++n)
      #pragma unroll
      for (int j = 0; j < 4; ++j)
        lgs[(wid * 16 + g * 4 + j) * 33 + n * 16 + l15] = accl[n][j] * (1.0f / 0.7f);
  }
  // lgs rows are wave-local: no block barrier needed (compiler inserts lgkm wait)

  // =========== top-2 + 2-way softmax + mem (wave-local rows of fz) ===========
  {
    int row = tid >> 2, q = tid & 3;
    const float* lp = lgs + row * 33 + q * 8;
    float m1 = -3.4e38f, m2 = -3.4e38f; int i1 = -1, i2 = -1;
    #pragma unroll
    for (int s = 0; s < 8; ++s) {
      float v = lp[s]; int idx = q * 8 + s;
      if (v > m1) { m2 = m1; i2 = i1; m1 = v; i1 = idx; }
      else if (v > m2) { m2 = v; i2 = idx; }
    }
    #pragma unroll
    for (int d = 1; d <= 2; d <<= 1) {
      float om1 = __shfl_xor(m1, d); int oi1 = __shfl_xor(i1, d);
      float om2 = __shfl_xor(m2, d); int oi2 = __shfl_xor(i2, d);
      bool take = (om1 > m1) || (om1 == m1 && oi1 < i1);
      if (take) {
        float nm2; int ni2;
        if (m1 > om2 || (m1 == om2 && i1 < oi2)) { nm2 = m1; ni2 = i1; }
        else { nm2 = om2; ni2 = oi2; }
        m1 = om1; i1 = oi1; m2 = nm2; i2 = ni2;
      } else {
        if (om1 > m2 || (om1 == m2 && oi1 < i2)) { m2 = om1; i2 = oi1; }
      }
    }
    float a1 = 1.0f / (1.0f + expf(m2 - m1));
    float a2 = 1.0f - a1;
    const float4* v1 = (const float4*)(mvw + i1 * 128 + q * 32);
    const float4* v2 = (const float4*)(mvw + i2 * 128 + q * 32);
    #pragma unroll
    for (int c = 0; c < 4; ++c) {
      float4 pa = v1[c * 2], pb = v1[c * 2 + 1];
      float4 ra = v2[c * 2], rb = v2[c * 2 + 1];
      u16x8 o;
      o[0] = f2bf(a1 * pa.x + a2 * ra.x); o[1] = f2bf(a1 * pa.y + a2 * ra.y);
      o[2] = f2bf(a1 * pa.z + a2 * ra.z); o[3] = f2bf(a1 * pa.w + a2 * ra.w);
      o[4] = f2bf(a1 * pb.x + a2 * rb.x); o[5] = f2bf(a1 * pb.y + a2 * rb.y);
      o[6] = f2bf(a1 * pb.z + a2 * rb.z); o[7] = f2bf(a1 * pb.w + a2 * rb.w);
      *(u16x8*)(fz + row * 264 + 128 + q * 32 + c * 8) = o;
    }
  }
  __syncthreads();                  // mem visible to all; lgs dead -> w3t may DMA over it

  // =========== GEMM3: h = gelu(fused @ w3 + b3)  [64 x 384], K=256, BK=32, NO barriers ===========
  {
    const u16* s3 = w3s + wid * 3072 + lane * 8;
    u16* d3 = w3t + wid * 3072;
    #pragma unroll
    for (int i = 0; i < 6; ++i) gload16(s3 + i * 512, d3 + i * 512);
  }
  f32x4 acc3[4][6];
  #pragma unroll
  for (int m = 0; m < 4; ++m)
    #pragma unroll
    for (int n = 0; n < 6; ++n) acc3[m][n] = (f32x4){0.f, 0.f, 0.f, 0.f};
  for (int kt = 0; kt < 8; ++kt) {
    WAIT_VM0;                       // my w3 tile (kt) landed
    u16x8 a3f[4], b3f[6];
    #pragma unroll
    for (int m = 0; m < 4; ++m)
      a3f[m] = *(const u16x8*)(fz + (m * 16 + l15) * 264 + kt * 32 + g * 8);
    #pragma unroll
    for (int n = 0; n < 6; ++n)
      b3f[n] = *(const u16x8*)(w3t + (wid * 96 + n * 16 + l15) * 32 + (g ^ bsw2) * 8);
    WAIT_LGKM0;
    if (kt < 7) {
      const u16* s3 = w3s + (kt + 1) * 12288 + wid * 3072 + lane * 8;
      u16* d3 = w3t + wid * 3072;
      #pragma unroll
      for (int i = 0; i < 6; ++i) gload16(s3 + i * 512, d3 + i * 512);
    }
    __builtin_amdgcn_s_setprio(1);
    #pragma unroll
    for (int m = 0; m < 4; ++m)
      #pragma unroll
      for (int n = 0; n < 6; ++n)
        acc3[m][n] = mfma16(a3f[m], b3f[n], acc3[m][n]);
    __builtin_amdgcn_s_setprio(0);
  }
  __syncthreads();                  // all fz reads done -> rowpart may alias

  // epilogue: per-row dot with w4, 16-lane shuffle reduce
  #pragma unroll
  for (int m = 0; m < 4; ++m) {
    float s0 = 0.f, s1 = 0.f, s2 = 0.f, s3 = 0.f;
    #pragma unroll
    for (int n = 0; n < 6; ++n) {
      int col = wid * 96 + n * 16 + l15;
      float bias = b3s[col], wv = w4s[col];
      s0 += gelu_exact(acc3[m][n][0] + bias) * wv;
      s1 += gelu_exact(acc3[m][n][1] + bias) * wv;
      s2 += gelu_exact(acc3[m][n][2] + bias) * wv;
      s3 += gelu_exact(acc3[m][n][3] + bias) * wv;
    }
    #pragma unroll
    for (int d = 1; d < 16; d <<= 1) {
      s0 += __shfl_xor(s0, d); s1 += __shfl_xor(s1, d);
      s2 += __shfl_xor(s2, d); s3 += __shfl_xor(s3, d);
    }
    if (l15 == 0) {
      int rb = m * 16 + g * 4;
      rowpart[(rb + 0) * 4 + wid] = s0;
      rowpart[(rb + 1) * 4 + wid] = s1;
      rowpart[(rb + 2) * 4 + wid] = s2;
      rowpart[(rb + 3) * 4 + wid] = s3;
    }
  }
  __syncthreads();
  if (tid < BM) {
    float lg = rowpart[tid * 4] + rowpart[tid * 4 + 1] + rowpart[tid * 4 + 2] +
               rowpart[tid * 4 + 3] + b4[0];
    out[row0 + tid] = 1.0f / (1.0f + expf(-lg));
  }
}

// ---------------- launch ----------------
extern "C" void kernel_launch(void* const* d_in, const int* in_sizes, int n_in,
                              void* d_out, int out_size, void* d_ws, size_t ws_size,
                              hipStream_t stream) {
  const float* x  = (const float*)d_in[0];
  const float* w1 = (const float*)d_in[1];
  const float* b1 = (const float*)d_in[2];
  const float* w2 = (const float*)d_in[3];
  const float* b2 = (const float*)d_in[4];
  const float* mk = (const float*)d_in[5];
  const float* mv = (const float*)d_in[6];
  const float* w3 = (const float*)d_in[7];
  const float* b3 = (const float*)d_in[8];
  const float* w4 = (const float*)d_in[9];
  const float* b4 = (const float*)d_in[10];

  u16* w1s = (u16*)d_ws;            // 393216 u16 (16 swizzled BK=64 tiles)
  u16* w2s = w1s + 393216;          // 49152 (6 BK=64 tiles)
  u16* w3s = w1s + 442368;          // 98304 (8 BK=32 tiles)

  prep_kernel<<<2112, 256, 0, stream>>>(w1, w2, w3, w1s, w2s, w3s);

  (void)hipFuncSetAttribute(reinterpret_cast<const void*>(fused_kernel),
                            hipFuncAttributeMaxDynamicSharedMemorySize, SMEM_BYTES);
  fused_kernel<<<NBLK, BDIM, SMEM_BYTES, stream>>>(x, w1s, b1, w2s, b2, mk, mv, w3s,
                                                   b3, w4, b4, (float*)d_out);
}